// Round 3
// baseline (471.265 us; speedup 1.0000x reference)
//
#include <hip/hip_runtime.h>
#include <cstdint>
#include <cstddef>

#define BB 16
#define CC 256
#define LL 4096
#define KNUM 1024
#define NFRM (BB * LL)      // 65536 frames

static const size_t NOUT = (size_t)BB * CC * LL;   // 16777216

// ------------------------------------------------------- K1: codebook norms
// Emulate ref fp32 semantics: s32 = fl32(exact sum of squares),
// rn = 1.0f/sqrtf(s32+1e-12f), en = fl32(v*rn). enorm2[k] = sum en^2 (loss).
__global__ void k_cbnorm(const float* __restrict__ cb, float* __restrict__ en,
                         float* __restrict__ enorm2) {
    __shared__ double wsum[4];
    const int k = blockIdx.x, c = threadIdx.x;
    float v = cb[(size_t)k * CC + c];
    double d = (double)v * (double)v;
#pragma unroll
    for (int m = 32; m >= 1; m >>= 1) d += __shfl_down(d, m);
    const int wv = c >> 6, ln = c & 63;
    if (ln == 0) wsum[wv] = d;
    __syncthreads();
    const double tot = wsum[0] + wsum[1] + wsum[2] + wsum[3];
    const float s32 = (float)tot;
    const float rn = 1.0f / sqrtf(s32 + 1e-12f);
    const float e = v * rn;                 // one fp32 rounding, like ref
    en[(size_t)k * CC + c] = e;
    double e2 = (double)e * (double)e;
#pragma unroll
    for (int m = 32; m >= 1; m >>= 1) e2 += __shfl_down(e2, m);
    __syncthreads();
    if (ln == 0) wsum[wv] = e2;
    __syncthreads();
    if (c == 0) enorm2[k] = (float)(wsum[0] + wsum[1] + wsum[2] + wsum[3]);
}

// ------------------------------- K2: per-frame rsqrt scale + ||xn||^2 (loss)
__global__ void k_xnorm(const float* __restrict__ x, float* __restrict__ rnx,
                        float* __restrict__ nxn) {
    const int tid = threadIdx.x;
    const int b = blockIdx.x >> 4;
    const int l0 = (blockIdx.x & 15) << 8;
    const float* xb = x + (size_t)b * CC * LL + l0;
    double s0 = 0.0, s1 = 0.0, s2 = 0.0, s3 = 0.0;
#pragma unroll 4
    for (int c = 0; c < CC; c += 4) {
        float v0 = xb[(size_t)(c + 0) * LL + tid];
        float v1 = xb[(size_t)(c + 1) * LL + tid];
        float v2 = xb[(size_t)(c + 2) * LL + tid];
        float v3 = xb[(size_t)(c + 3) * LL + tid];
        s0 += (double)v0 * v0; s1 += (double)v1 * v1;
        s2 += (double)v2 * v2; s3 += (double)v3 * v3;
    }
    const float s32 = (float)((s0 + s1) + (s2 + s3));
    const float rn = 1.0f / sqrtf(s32 + 1e-12f);
    const int f = b * LL + l0 + tid;
    rnx[f] = rn;
    nxn[f] = s32 * rn * rn;
}

// ---------------- K3: fp32 sim GEMM (sequential FMA over c) + fp32 argmax
// 128 frames x all 1024 k per block. Sims bit-match a sequential-FMA fp32
// contraction of (xn, en); argmax = first max (lowest k), like np.argmax.
__global__ __launch_bounds__(256, 2) void k_argmax(
    const float* __restrict__ x, const float* __restrict__ en,
    const float* __restrict__ rnx, int* __restrict__ sidx,
    float* __restrict__ sw) {
    __shared__ float Xs[16][132];
    __shared__ float Es[16][132];
    __shared__ float rns[128];
    __shared__ float bvs[128];
    __shared__ int   bks[128];

    const int tid = threadIdx.x;
    const int tx = tid & 15, ty = tid >> 4;
    const int b = blockIdx.x >> 5;
    const int l0 = (blockIdx.x & 31) << 7;
    const float* xb = x + (size_t)b * CC * LL + l0;

    if (tid < 128) rns[tid] = rnx[b * LL + l0 + tid];
    __syncthreads();

    const int xl4 = (tid & 31) << 2;  // staged l column, step 4
    const int xcr = tid >> 5;         // 0..7
    const int ec4 = (tid & 3) << 2;   // c col 0,4,8,12
    const int ekr = tid >> 2;         // 0..63

    const float rnl0 = rns[xl4 + 0], rnl1 = rns[xl4 + 1];
    const float rnl2 = rns[xl4 + 2], rnl3 = rns[xl4 + 3];

    float rbest[8];
    int   rbk[8];
#pragma unroll
    for (int i = 0; i < 8; ++i) { rbest[i] = -3e38f; rbk[i] = 0; }

    for (int kc = 0; kc < 8; ++kc) {
        float acc[8][8];
#pragma unroll
        for (int i = 0; i < 8; ++i)
#pragma unroll
            for (int j = 0; j < 8; ++j) acc[i][j] = 0.f;

        for (int ct = 0; ct < 16; ++ct) {
            __syncthreads();
#pragma unroll
            for (int i = 0; i < 2; ++i) {  // X tile: 16c x 128l, scaled -> xn
                int c = xcr + (i << 3);
                float4 v = *(const float4*)&xb[(size_t)(ct * 16 + c) * LL + xl4];
                v.x *= rnl0; v.y *= rnl1; v.z *= rnl2; v.w *= rnl3;
                *(float4*)&Xs[c][xl4] = v;
            }
#pragma unroll
            for (int i = 0; i < 2; ++i) {  // E tile: 16c x 128k (transposed)
                int kk = ekr + (i << 6);
                float4 v = *(const float4*)&en[(size_t)(kc * 128 + kk) * CC + ct * 16 + ec4];
                Es[ec4 + 0][kk] = v.x;
                Es[ec4 + 1][kk] = v.y;
                Es[ec4 + 2][kk] = v.z;
                Es[ec4 + 3][kk] = v.w;
            }
            __syncthreads();
#pragma unroll
            for (int cs = 0; cs < 16; ++cs) {   // c = ct*16+cs ascending 0..255
                float xr[8], er[8];
                *(float4*)&xr[0] = *(const float4*)&Xs[cs][ty << 2];
                *(float4*)&xr[4] = *(const float4*)&Xs[cs][64 + (ty << 2)];
                *(float4*)&er[0] = *(const float4*)&Es[cs][tx << 2];
                *(float4*)&er[4] = *(const float4*)&Es[cs][64 + (tx << 2)];
#pragma unroll
                for (int fi = 0; fi < 8; ++fi)
#pragma unroll
                    for (int ki = 0; ki < 8; ++ki)
                        acc[fi][ki] = fmaf(xr[fi], er[ki], acc[fi][ki]);
            }
        }
        // chunk argmax (fp32, lowest-k ties) -> merge into running
#pragma unroll
        for (int fi = 0; fi < 8; ++fi) {
            float m1 = acc[fi][0];
            int   i1 = kc * 128 + (tx << 2);
#pragma unroll
            for (int ki = 1; ki < 8; ++ki) {     // kg ascending in ki
                int kg = kc * 128 + ((ki >> 2) << 6) + (tx << 2) + (ki & 3);
                float v = acc[fi][ki];
                if (v > m1) { m1 = v; i1 = kg; }
            }
#pragma unroll
            for (int m = 1; m < 16; m <<= 1) {
                float o = __shfl_xor(m1, m);
                int  oi = __shfl_xor(i1, m);
                if (o > m1 || (o == m1 && oi < i1)) { m1 = o; i1 = oi; }
            }
            if (m1 > rbest[fi] || (m1 == rbest[fi] && i1 < rbk[fi])) {
                rbest[fi] = m1; rbk[fi] = i1;
            }
        }
    }
    if (tx == 0) {
#pragma unroll
        for (int fi = 0; fi < 8; ++fi) {
            int fl = ((fi >> 2) << 6) + (ty << 2) + (fi & 3);
            bvs[fl] = rbest[fi];
            bks[fl] = rbk[fi];
        }
    }
    __syncthreads();
    if (tid < 128) {
        int f = b * LL + l0 + tid;
        sidx[f] = bks[tid];
        sw[f] = bvs[tid];      // sim = xn . en_winner (bit-exact fp32)
    }
}

// ----------------------------------- K4: gather winners -> out, loss reduce
__global__ void k_gather(const float* __restrict__ en, const int* __restrict__ sidx,
                         const float* __restrict__ sw, const float* __restrict__ nxn,
                         const float* __restrict__ enorm2, float* __restrict__ out,
                         float* __restrict__ loss) {
    __shared__ float ens[32][257];
    __shared__ int lidx[32];
    const int tid = threadIdx.x;
    const int b = blockIdx.x >> 7;
    const int l0 = (blockIdx.x & 127) << 5;
    const int fbase = b * LL + l0;
    if (tid < 32) lidx[tid] = sidx[fbase + tid];
    __syncthreads();
    for (int j = 0; j < 32; ++j)
        ens[j][tid] = en[(size_t)lidx[j] * CC + tid];
    __syncthreads();
    const int jj = tid & 31;
    const int c0 = (tid >> 5) << 5;
    float* ob = out + (size_t)b * CC * LL + l0;
#pragma unroll 4
    for (int ci = 0; ci < 32; ++ci) {
        int c = c0 + ci;
        ob[(size_t)c * LL + jj] = ens[jj][c];
    }
    // loss term: ||xn||^2 + ||q||^2 - 2*sim
    float part = 0.f;
    if (tid < 32) {
        int f = fbase + tid;
        part = nxn[f] + enorm2[lidx[tid]] - 2.0f * sw[f];
    }
    if (tid < 64) {
#pragma unroll
        for (int m = 32; m >= 1; m >>= 1) part += __shfl_xor(part, m);
        if (tid == 0) atomicAdd(loss, part * (1.25f / 16777216.f));
    }
}

// ------------------------------------------------------------------- launch
extern "C" void kernel_launch(void* const* d_in, const int* in_sizes, int n_in,
                              void* d_out, int out_size, void* d_ws, size_t ws_size,
                              hipStream_t stream) {
    const float* x = (const float*)d_in[0];
    const float* cb = (const float*)d_in[1];
    float* out = (float*)d_out;
    char* ws = (char*)d_ws;

    float* en     = (float*)(ws);                  // 1 MB
    float* enorm2 = (float*)(ws + 1048576);        // 4 KB
    float* rnx    = (float*)(ws + 1052672);        // 256 KB
    float* nxn    = (float*)(ws + 1314816);        // 256 KB
    int*   sidx   = (int*)(ws + 1576960);          // 256 KB
    float* sw     = (float*)(ws + 1839104);        // 256 KB

    hipMemsetAsync(out + NOUT, 0, sizeof(float), stream);

    k_cbnorm<<<KNUM, 256, 0, stream>>>(cb, en, enorm2);
    k_xnorm<<<BB * (LL / 256), 256, 0, stream>>>(x, rnx, nxn);
    k_argmax<<<BB * (LL / 128), 256, 0, stream>>>(x, en, rnx, sidx, sw);
    k_gather<<<BB * (LL / 32), 256, 0, stream>>>(en, sidx, sw, nxn, enorm2, out, out + NOUT);
}